// Round 1
// baseline (220.523 us; speedup 1.0000x reference)
//
#include <hip/hip_runtime.h>

// postprocess_ssfd: 6-level detection-head postprocess.
// out[(i*W+j)*5+k] = mask(i,j) ? (k<4 ? x1[i] : sc[i]) : 0
//   mask(i,j) = (cls0[i,j] - cls1[i,j]) < ln(19)   [== softmax p1 > 0.05]
//   x1[i] = s/2 + i*s + reg0[0,i]*0.1*4s - 4s*exp(reg2[0,i]*0.2)/2
//   sc[i] = 1/(1+exp(cls0[0,i]-cls1[0,i]))
// Only row 0 of reg/score feeds x1/sc -> precompute 4032 rows into ws.

namespace {

constexpr float LN19 = 2.9444389791664403f; // ln(19): p1>0.05 boundary

struct Params {
  const float* cls[6];
  const float* reg[6];
  float2* ws;            // 4032 x {x1, sc}
  float* out;
  unsigned rowBase[6];   // ws row offset per level
  unsigned outBase[6];   // output float offset per level
  unsigned blockBase[6]; // cumulative block count per level (main kernel)
  unsigned logW[6];
};

// constant-index unrolled select: avoids runtime-indexed kernarg arrays
// (rule #20: dynamic indexing can spill to scratch)
template <typename T>
__device__ __forceinline__ T sel6(const T (&a)[6], int lvl) {
  T r = a[0];
#pragma unroll
  for (int L = 1; L < 6; ++L) r = (lvl == L) ? a[L] : r;
  return r;
}

} // namespace

// --- precompute per-row {x1, sc} for all 4032 rows (tiny, latency-bound) ---
__global__ __launch_bounds__(256) void pp_rows(Params p) {
  unsigned gid = blockIdx.x * 256u + threadIdx.x;
  if (gid >= 4032u) return;
  int lvl = 0;
#pragma unroll
  for (int L = 1; L < 6; ++L) lvl += (gid >= p.rowBase[L]) ? 1 : 0;
  unsigned i    = gid - sel6(p.rowBase, lvl);
  unsigned logW = sel6(p.logW, lvl);
  unsigned HW   = 1u << (2u * logW);
  const float* cls = sel6(p.cls, lvl);
  const float* reg = sel6(p.reg, lvl);

  float s  = (float)(4 << lvl);     // stride 4,8,16,32,64,128
  float s4 = 4.0f * s;
  // sc: softmax p1 at (row 0, col i) -> logistic of logit difference
  float c0 = cls[i];
  float c1 = cls[HW + i];
  float sc = 1.0f / (1.0f + expf(c0 - c1));
  // x1: mirror reference op order for rounding parity
  float l0 = reg[i];                // reg[0,0,0,i]
  float l2 = reg[2u * HW + i];      // reg[0,2,0,i]
  float axc = 0.5f * s + (float)i * s;
  float cx  = axc + (l0 * 0.1f) * s4;
  float x1  = cx - (s4 * expf(l2 * 0.2f)) * 0.5f;
  p.ws[gid] = make_float2(x1, sc);
}

// --- main: one thread per output float4 (coalesced stores) ---
__global__ __launch_bounds__(256) void pp_out(Params p) {
  unsigned b = blockIdx.x;
  int lvl = 0;
#pragma unroll
  for (int L = 1; L < 6; ++L) lvl += (b >= p.blockBase[L]) ? 1 : 0;
  unsigned bl   = b - sel6(p.blockBase, lvl);
  unsigned logW = sel6(p.logW, lvl);
  unsigned HW   = 1u << (2u * logW);
  const float*  cls = sel6(p.cls, lvl);
  const float2* ws  = p.ws + sel6(p.rowBase, lvl);
  float*        out = p.out + sel6(p.outBase, lvl);

  unsigned f  = (bl * 256u + threadIdx.x) * 4u; // float index within level
  unsigned r0 = f / 5u;                         // magic-mul div
  unsigned k0 = f - r0 * 5u;
  unsigned r1 = r0 + 1u;
  if (r1 > HW - 1u) r1 = HW - 1u;               // clamp (safe, last row dup)

  // mask + row values for the (up to) 2 rows this float4 spans
  float d0 = cls[r0] - cls[HW + r0];
  float d1 = cls[r1] - cls[HW + r1];
  float2 w0 = ws[r0 >> logW];
  float2 w1 = ws[r1 >> logW];
  float a0 = (d0 < LN19) ? w0.x : 0.0f;  // masked x1, row r0
  float b0 = (d0 < LN19) ? w0.y : 0.0f;  // masked sc, row r0
  float a1 = (d1 < LN19) ? w1.x : 0.0f;
  float b1 = (d1 < LN19) ? w1.y : 0.0f;

  float v[4];
  unsigned k = k0;
  bool sec = false;
#pragma unroll
  for (int u = 0; u < 4; ++u) { // walk k mod 5; at most one row switch
    float va = sec ? a1 : a0;
    float vb = sec ? b1 : b0;
    v[u] = (k == 4u) ? vb : va;
    ++k;
    if (k == 5u) { k = 0u; sec = true; }
  }
  *reinterpret_cast<float4*>(out + f) = make_float4(v[0], v[1], v[2], v[3]);
}

extern "C" void kernel_launch(void* const* d_in, const int* in_sizes, int n_in,
                              void* d_out, int out_size, void* d_ws, size_t ws_size,
                              hipStream_t stream) {
  Params p;
  unsigned rowBase = 0, outBase = 0, blockBase = 0;
  for (int l = 0; l < 6; ++l) {
    unsigned logW = 11u - (unsigned)l;        // W = 2048,1024,512,256,128,64
    unsigned W = 1u << logW;
    p.cls[l] = (const float*)d_in[2 * l];
    p.reg[l] = (const float*)d_in[2 * l + 1];
    p.logW[l] = logW;
    p.rowBase[l] = rowBase;
    p.outBase[l] = outBase;
    p.blockBase[l] = blockBase;
    rowBase  += W;
    outBase  += W * W * 5u;
    blockBase += (W * W * 5u) >> 10;          // / (4 floats * 256 threads)
  }
  p.ws  = (float2*)d_ws;   // needs 4032*8 = 32 KiB
  p.out = (float*)d_out;

  pp_rows<<<16, 256, 0, stream>>>(p);              // 4032 rows
  pp_out<<<blockBase, 256, 0, stream>>>(p);        // 27300 blocks total
}

// Round 5
// 216.166 us; speedup vs baseline: 1.0202x; 1.0202x over previous
//
#include <hip/hip_runtime.h>

// postprocess_ssfd: 6-level detection-head postprocess, single fused kernel.
// out[(i*W+j)*5+k] = mask(i,j) ? (k<4 ? x1[i] : sc[i]) : 0
//   mask(i,j) = (cls0[i,j] - cls1[i,j]) < ln(19)   [== softmax p1 > 0.05]
//   x1[i] = s/2 + i*s + reg0[0,i]*0.1*4s - 4s*exp(reg2[0,i]*0.2)/2
//   sc[i] = 1/(1+exp(cls0[0,i]-cls1[0,i]))
// Only row 0 of reg/cls feeds x1/sc; those vectors are <=32KB/level and
// L2-hot, so each thread computes them inline (no ws, no 2nd launch).

namespace {

constexpr float LN19 = 2.9444389791664403f; // ln(19): p1>0.05 boundary

// native clang vector: __builtin_nontemporal_store requires it
// (HIP's float4 is a class and is rejected — R3 compile error)
typedef float floatx4 __attribute__((ext_vector_type(4)));

struct Params {
  const float* cls[6];
  const float* reg[6];
  float* out;
  unsigned outBase[6];   // output float offset per level
  unsigned blockBase[6]; // cumulative block count per level
  unsigned logW[6];
};

// constant-index unrolled select: avoids runtime-indexed kernarg arrays
// (rule #20: dynamic indexing can spill to scratch)
template <typename T>
__device__ __forceinline__ T sel6(const T (&a)[6], int lvl) {
  T r = a[0];
#pragma unroll
  for (int L = 1; L < 6; ++L) r = (lvl == L) ? a[L] : r;
  return r;
}

} // namespace

// one thread per output float4 (fully coalesced 16B stores)
__global__ __launch_bounds__(256) void pp_fused(Params p) {
  unsigned b = blockIdx.x;
  int lvl = 0;
#pragma unroll
  for (int L = 1; L < 6; ++L) lvl += (b >= p.blockBase[L]) ? 1 : 0;
  unsigned bl   = b - sel6(p.blockBase, lvl);
  unsigned logW = sel6(p.logW, lvl);
  unsigned HW   = 1u << (2u * logW);
  const float* cls = sel6(p.cls, lvl);
  const float* reg = sel6(p.reg, lvl);
  float*       out = p.out + sel6(p.outBase, lvl);

  unsigned f  = (bl * 256u + threadIdx.x) * 4u; // float index within level
  unsigned r0 = f / 5u;                         // pixel index (magic-mul div)
  unsigned k0 = f - r0 * 5u;
  unsigned r1 = r0 + 1u;
  if (r1 > HW - 1u) r1 = HW - 1u;               // clamp (last-pixel dup, safe)

  // masks for the (up to) 2 pixels this float4 spans
  float d0 = cls[r0] - cls[HW + r0];
  float d1 = cls[r1] - cls[HW + r1];

  // per-row {x1, sc} computed inline; row-0 vectors are L1/L2-hot
  unsigned i0 = r0 >> logW;
  unsigned i1 = r1 >> logW;
  float s  = (float)(4 << lvl);                 // stride 4,8,16,32,64,128
  float s4 = 4.0f * s;

  // row i0 — keep exact op order from the verified R1 kernel (bitwise parity)
  float sc0, x10;
  {
    float c0 = cls[i0];
    float c1 = cls[HW + i0];
    sc0 = 1.0f / (1.0f + expf(c0 - c1));
    float l0 = reg[i0];                         // reg[0,0,0,i]
    float l2 = reg[2u * HW + i0];               // reg[0,2,0,i]
    float axc = 0.5f * s + (float)i0 * s;
    float cx  = axc + (l0 * 0.1f) * s4;
    x10 = cx - (s4 * expf(l2 * 0.2f)) * 0.5f;
  }
  float sc1 = sc0, x11 = x10;
  if (i1 != i0) {                               // rare: row-boundary crossing
    float c0 = cls[i1];
    float c1 = cls[HW + i1];
    sc1 = 1.0f / (1.0f + expf(c0 - c1));
    float l0 = reg[i1];
    float l2 = reg[2u * HW + i1];
    float axc = 0.5f * s + (float)i1 * s;
    float cx  = axc + (l0 * 0.1f) * s4;
    x11 = cx - (s4 * expf(l2 * 0.2f)) * 0.5f;
  }

  float a0 = (d0 < LN19) ? x10 : 0.0f;  // masked x1, pixel r0
  float b0 = (d0 < LN19) ? sc0 : 0.0f;  // masked sc, pixel r0
  float a1 = (d1 < LN19) ? x11 : 0.0f;
  float b1 = (d1 < LN19) ? sc1 : 0.0f;

  floatx4 v;
  unsigned k = k0;
  bool sec = false;
#pragma unroll
  for (int u = 0; u < 4; ++u) { // walk k mod 5; at most one pixel switch
    float va = sec ? a1 : a0;
    float vb = sec ? b1 : b0;
    v[u] = (k == 4u) ? vb : va;
    ++k;
    if (k == 5u) { k = 0u; sec = true; }
  }
  // out is write-once-never-read: nontemporal store skips L2 write-allocate
  __builtin_nontemporal_store(v, reinterpret_cast<floatx4*>(out + f));
}

extern "C" void kernel_launch(void* const* d_in, const int* in_sizes, int n_in,
                              void* d_out, int out_size, void* d_ws, size_t ws_size,
                              hipStream_t stream) {
  Params p;
  unsigned outBase = 0, blockBase = 0;
  for (int l = 0; l < 6; ++l) {
    unsigned logW = 11u - (unsigned)l;        // W = 2048,1024,512,256,128,64
    unsigned W = 1u << logW;
    p.cls[l] = (const float*)d_in[2 * l];
    p.reg[l] = (const float*)d_in[2 * l + 1];
    p.logW[l] = logW;
    p.outBase[l] = outBase;
    p.blockBase[l] = blockBase;
    outBase  += W * W * 5u;
    blockBase += (W * W * 5u) >> 10;          // / (4 floats * 256 threads)
  }
  p.out = (float*)d_out;

  pp_fused<<<blockBase, 256, 0, stream>>>(p); // 27300 blocks, all full
}